// Round 3
// baseline (275.858 us; speedup 1.0000x reference)
//
#include <hip/hip_runtime.h>

typedef __attribute__((ext_vector_type(8))) short bf16x8;
typedef __attribute__((ext_vector_type(4))) float f32x4;
typedef __attribute__((ext_vector_type(4))) unsigned short u16x4;
typedef unsigned short ushort_t;

#define HW_ 16384
#define LDSTR 144   // 72 bf16 elems * 2B per LDS row

__device__ __forceinline__ float bf2f(unsigned short u) {
  union { unsigned u; float f; } x; x.u = ((unsigned)u) << 16; return x.f;
}
__device__ __forceinline__ unsigned short f2bf(float f) {
  union { float f; unsigned u; } x; x.f = f;
  unsigned r = x.u + 0x7fffu + ((x.u >> 16) & 1u);
  return (unsigned short)(r >> 16);
}
// XOR-swizzled LDS byte offset for transposed tile xT[p][c]
__device__ __forceinline__ int swz(int row, int cb) {
  return row * LDSTR + (cb ^ (((row >> 3) & 7) << 4));
}

#define MFMA(a, b, c) __builtin_amdgcn_mfma_f32_16x16x32_bf16(a, b, c, 0, 0, 0)

__device__ __forceinline__ bf16x8 ld_wfrag(const float* p) {
  f32x4 a = *reinterpret_cast<const f32x4*>(p);
  f32x4 c = *reinterpret_cast<const f32x4*>(p + 4);
  bf16x8 r;
  #pragma unroll
  for (int j = 0; j < 4; ++j) { r[j] = (short)f2bf(a[j]); r[j + 4] = (short)f2bf(c[j]); }
  return r;
}

__global__ __launch_bounds__(256, 2) void gci_kernel(
    const float* __restrict__ x1, const float* __restrict__ x2,
    const float* __restrict__ x3, const float* __restrict__ x4,
    const float* __restrict__ wI, const float* __restrict__ bI,
    const float* __restrict__ wS, const float* __restrict__ bS,
    const float* __restrict__ wG, const float* __restrict__ bG,
    float* __restrict__ out)
{
  // 6 buffers of [64 pixels][72 bf16]: xT0..xT3, xsumT, aggT  (55296 B)
  __shared__ __align__(16) char ldsb[6 * 64 * LDSTR];

  const int t    = threadIdx.x;
  const int lane = t & 63;
  const int w    = t >> 6;
  const int lr   = lane & 15;
  const int lg   = lane >> 4;

  const int tile = blockIdx.x;
  const int pix0 = tile * 64;
  const int b    = pix0 >> 14;          // image index (HW = 16384)
  const int pimg = pix0 & (HW_ - 1);    // pixel offset within image

  const float* xin[4] = {x1, x2, x3, x4};

  // ---------- stage x1..x4 transposed (bf16) into LDS, accumulate xsum ----------
  #pragma unroll
  for (int ch2 = 0; ch2 < 4; ++ch2) {
    const int q  = ch2 * 256 + t;       // 1024 chunks: 64 channels x 16 pixel-quads
    const int c  = q >> 4;
    const int p4 = q & 15;
    const int goff = (b * 64 + c) * HW_ + pimg + p4 * 4;
    float xs[4] = {0.f, 0.f, 0.f, 0.f};
    #pragma unroll
    for (int i = 0; i < 4; ++i) {
      f32x4 v = *reinterpret_cast<const f32x4*>(xin[i] + goff);
      #pragma unroll
      for (int j = 0; j < 4; ++j) {
        *(unsigned short*)(ldsb + i * 9216 + swz(p4 * 4 + j, c * 2)) = f2bf(v[j]);
        xs[j] += v[j];
      }
    }
    #pragma unroll
    for (int j = 0; j < 4; ++j)
      *(unsigned short*)(ldsb + 36864 + swz(p4 * 4 + j, c * 2)) = f2bf(xs[j]);
  }

  // ---------- per-wave weight A-fragments (fp32 in global, bf16 frags) ----------
  // A-frag(m,kk): lane holds W[m*16 + (l&15)][kk*32 + (l>>4)*8 + j], j=0..7
  bf16x8 fWi[4][2], fD[4][2], fG1[4][2], fG2[4][2];
  #pragma unroll
  for (int m = 0; m < 4; ++m) {
    #pragma unroll
    for (int kk = 0; kk < 2; ++kk) {
      const int row = m * 16 + lr, col = kk * 32 + lg * 8;
      const float* pwi = wI + row * 64 + col;
      const float* pws = wS + row * 64 + col;
      fWi[m][kk] = ld_wfrag(pwi);
      bf16x8 d;
      #pragma unroll
      for (int j = 0; j < 8; ++j) d[j] = (short)f2bf(pws[j] - pwi[j]);
      fD[m][kk]  = d;
      fG1[m][kk] = ld_wfrag(wG + row * 128 + col);
      fG2[m][kk] = ld_wfrag(wG + row * 128 + 64 + col);
    }
  }

  // biases per lane: C/D layout row = m*16 + lg*4 + r
  float biasA[4][4], biasG[4][4];
  #pragma unroll
  for (int m = 0; m < 4; ++m) {
    #pragma unroll
    for (int r = 0; r < 4; ++r) {
      const int ch = m * 16 + lg * 4 + r;
      biasA[m][r] = bS[ch] + 3.f * bI[ch];
      biasG[m][r] = bG[ch];
    }
  }

  __syncthreads();

  const int prow = w * 16 + lr;   // this lane's pixel (tile-local): B-frag col & D col

  // ---------- Abase = W_inter * xsum + (b_self + 3 b_inter) ----------
  bf16x8 xsB[2];
  #pragma unroll
  for (int kk = 0; kk < 2; ++kk)
    xsB[kk] = *reinterpret_cast<const bf16x8*>(ldsb + 36864 + swz(prow, kk * 64 + lg * 16));
  f32x4 Abase[4];
  #pragma unroll
  for (int m = 0; m < 4; ++m) {
    f32x4 a = {biasA[m][0], biasA[m][1], biasA[m][2], biasA[m][3]};
    Abase[m] = a;
  }
  #pragma unroll
  for (int kk = 0; kk < 2; ++kk)
    #pragma unroll
    for (int m = 0; m < 4; ++m)
      Abase[m] = MFMA(fWi[m][kk], xsB[kk], Abase[m]);

  // ---------- per tensor: agg + gate + residual + store ----------
  #pragma unroll
  for (int i = 0; i < 4; ++i) {
    bf16x8 xB[2];
    #pragma unroll
    for (int kk = 0; kk < 2; ++kk)
      xB[kk] = *reinterpret_cast<const bf16x8*>(ldsb + i * 9216 + swz(prow, kk * 64 + lg * 16));

    // agg = relu(D * x_i + Abase)
    f32x4 agg[4];
    #pragma unroll
    for (int m = 0; m < 4; ++m) agg[m] = Abase[m];
    #pragma unroll
    for (int kk = 0; kk < 2; ++kk)
      #pragma unroll
      for (int m = 0; m < 4; ++m)
        agg[m] = MFMA(fD[m][kk], xB[kk], agg[m]);

    // pack relu(agg) to bf16 into aggT (waves touch disjoint rows; intra-wave dep)
    #pragma unroll
    for (int m = 0; m < 4; ++m) {
      u16x4 pk;
      #pragma unroll
      for (int r = 0; r < 4; ++r) pk[r] = f2bf(fmaxf(agg[m][r], 0.f));
      *(u16x4*)(ldsb + 46080 + swz(prow, m * 32 + lg * 8)) = pk;
    }
    bf16x8 aB[2];
    #pragma unroll
    for (int kk = 0; kk < 2; ++kk)
      aB[kk] = *reinterpret_cast<const bf16x8*>(ldsb + 46080 + swz(prow, kk * 64 + lg * 16));

    // out = x + Wg1*x + Wg2*agg + b_gate
    f32x4 o[4];
    #pragma unroll
    for (int m = 0; m < 4; ++m) {
      f32x4 a = {biasG[m][0], biasG[m][1], biasG[m][2], biasG[m][3]};
      o[m] = a;
    }
    #pragma unroll
    for (int kk = 0; kk < 2; ++kk)
      #pragma unroll
      for (int m = 0; m < 4; ++m) {
        o[m] = MFMA(fG1[m][kk], xB[kk], o[m]);
        o[m] = MFMA(fG2[m][kk], aB[kk], o[m]);
      }

    const int obase = i * 16777216 + b * 64 * HW_ + pimg + prow;
    #pragma unroll
    for (int m = 0; m < 4; ++m) {
      u16x4 xr = *(const u16x4*)(ldsb + i * 9216 + swz(prow, m * 32 + lg * 8));
      #pragma unroll
      for (int r = 0; r < 4; ++r) {
        const float v = o[m][r] + bf2f(xr[r]);
        const int ch = m * 16 + lg * 4 + r;
        out[obase + ch * HW_] = v;
      }
    }
  }
}

extern "C" void kernel_launch(void* const* d_in, const int* in_sizes, int n_in,
                              void* d_out, int out_size, void* d_ws, size_t ws_size,
                              hipStream_t stream) {
  (void)in_sizes; (void)n_in; (void)d_ws; (void)ws_size; (void)out_size;
  gci_kernel<<<dim3(4096), dim3(256), 0, stream>>>(
      (const float*)d_in[0], (const float*)d_in[1],
      (const float*)d_in[2], (const float*)d_in[3],
      (const float*)d_in[4], (const float*)d_in[5],
      (const float*)d_in[6], (const float*)d_in[7],
      (const float*)d_in[8], (const float*)d_in[9],
      (float*)d_out);
}